// Round 18
// baseline (153.742 us; speedup 1.0000x reference)
//
#include <hip/hip_runtime.h>

#define N_NODESC 50000
#define E0C      800000
#define E_TOTC   850000
#define IN_CHC   128
#define HCC      128   // HEADS*HID
#define HEADSC   4
#define OUT_CHC  16
#define NEG_SLOPE 0.2f
#define G1M      64                          // rows per block in k_gemm1 (MFMA)
#define NG1      ((N_NODESC + G1M - 1)/G1M)  // 782 gemm blocks
#define NBUCK    196                         // ceil(50000/256) dst buckets
#define BNODES   256                         // nodes per bucket (dst>>8)
#define SBLK     128                         // binning blocks
#define CHUNK    6656                        // edges per binning block (128*6656 >= 850000)

typedef __attribute__((ext_vector_type(8))) short bf16x8;
typedef __attribute__((ext_vector_type(4))) float f32x4;

__device__ __forceinline__ float lrelu(float v){ return v > 0.f ? v : NEG_SLOPE * v; }

__device__ __forceinline__ unsigned int f2bf(float f){
  unsigned int b = __float_as_uint(f);
  return (b + 0x7fffu + ((b >> 16) & 1u)) >> 16;
}
__device__ __forceinline__ float bf2f(unsigned int lo16){
  return __uint_as_float(lo16 << 16);
}

// One-time W1 pre-pack: bf16, transposed [n][k], MFMA swizzle baked in. 32 KB out.
__global__ void __launch_bounds__(256) k_prep(const float* __restrict__ W1, unsigned short* __restrict__ Wp){
  int tid = threadIdx.x;
  for (int i = tid; i < IN_CHC*HCC; i += 256){
    int n = i >> 7, k = i & 127;
    Wp[i ^ ((n & 7) << 3)] = (unsigned short)f2bf(W1[(size_t)k*HCC + n]);
  }
}

// Fused: blocks [0,NG1) do MFMA x@W1; blocks [NG1,NG1+SBLK) do binA histogram.
__global__ void __launch_bounds__(256) k_gemm1A(const float* __restrict__ x, const unsigned short* __restrict__ Wp,
        const float* __restrict__ a_s, const float* __restrict__ a_d,
        unsigned int* __restrict__ h1b, float* __restrict__ al_s, float* __restrict__ al_d,
        const int* __restrict__ ei, int* __restrict__ bh)
{
  __shared__ __align__(16) unsigned short Wt[IN_CHC*HCC];  // [n][k], swizzled
  __shared__ __align__(16) unsigned short xt[G1M*IN_CHC];  // [m][k], swizzled
  __shared__ int hh[NBUCK];
  int tid = threadIdx.x, lane = tid & 63, wave = tid >> 6;

  if (blockIdx.x >= NG1){            // ---- binA role ----
    int b = blockIdx.x - NG1;
    for (int i = tid; i < NBUCK; i += 256) hh[i] = 0;
    __syncthreads();
    int e0 = b*CHUNK, e1 = e0 + CHUNK; if (e1 > E_TOTC) e1 = E_TOTC;
    for (int e = e0 + tid; e < e1; e += 256){
      int d = (e < E0C) ? ei[E0C + e] : (e - E0C);
      atomicAdd(&hh[d >> 8], 1);
    }
    __syncthreads();
    for (int i = tid; i < NBUCK; i += 256) bh[i*SBLK + b] = hh[i];   // transposed [bucket][block]
    return;
  }

  // ---- gemm role ----
  int row0 = blockIdx.x * G1M;
  // stage pre-packed W (coalesced uint4 copies, swizzle already baked in)
  for (int i = tid*8; i < IN_CHC*HCC; i += 256*8)
    *(uint4*)&Wt[i] = *(const uint4*)&Wp[i];
  {
    int r  = tid >> 2;
    int kc = (tid & 3) * 32;
    int rr = row0 + r; if (rr > N_NODESC-1) rr = N_NODESC-1;
    const float* xp = &x[(size_t)rr*IN_CHC + kc];
    #pragma unroll
    for (int j = 0; j < 32; j += 8){
      unsigned int u0 = f2bf(xp[j+0]) | (f2bf(xp[j+1]) << 16);
      unsigned int u1 = f2bf(xp[j+2]) | (f2bf(xp[j+3]) << 16);
      unsigned int u2 = f2bf(xp[j+4]) | (f2bf(xp[j+5]) << 16);
      unsigned int u3 = f2bf(xp[j+6]) | (f2bf(xp[j+7]) << 16);
      int idx = (r*128 + kc + j) ^ ((r & 7) << 3);
      *(uint4*)&xt[idx] = make_uint4(u0,u1,u2,u3);
    }
  }
  __syncthreads();

  int rw = wave * 16;
  f32x4 acc[8];
  #pragma unroll
  for (int t = 0; t < 8; t++) acc[t] = (f32x4){0.f,0.f,0.f,0.f};
  #pragma unroll
  for (int kk = 0; kk < 128; kk += 32){
    int m  = rw + (lane & 15);
    int ks = kk + (lane >> 4)*8;
    bf16x8 afrag = *(bf16x8*)&xt[(m*128 + ks) ^ ((m & 7) << 3)];
    #pragma unroll
    for (int t = 0; t < 8; t++){
      int n = t*16 + (lane & 15);
      bf16x8 bfrag = *(bf16x8*)&Wt[(n*128 + ks) ^ ((n & 7) << 3)];
      acc[t] = __builtin_amdgcn_mfma_f32_16x16x32_bf16(afrag, bfrag, acc[t], 0, 0, 0);
    }
  }

  float asv[8], adv[8];
  #pragma unroll
  for (int t = 0; t < 8; t++){
    asv[t] = a_s[t*16 + (lane & 15)];
    adv[t] = a_d[t*16 + (lane & 15)];
  }
  #pragma unroll
  for (int r = 0; r < 4; r++){
    int row = row0 + rw + (lane >> 4)*4 + r;
    bool ok = (row < N_NODESC);
    #pragma unroll
    for (int t = 0; t < 8; t++){
      float v = acc[t][r];
      float o = __shfl_xor(v, 1, 64);
      int c = t*16 + (lane & 15);
      if (ok && ((c & 1) == 0))
        h1b[(size_t)row*64 + (c >> 1)] = f2bf(v) | (f2bf(o) << 16);
    }
    #pragma unroll
    for (int h = 0; h < 4; h++){
      float ps = acc[2*h][r]*asv[2*h] + acc[2*h+1][r]*asv[2*h+1];
      float pd = acc[2*h][r]*adv[2*h] + acc[2*h+1][r]*adv[2*h+1];
      #pragma unroll
      for (int m = 1; m < 16; m <<= 1){ ps += __shfl_xor(ps, m, 64); pd += __shfl_xor(pd, m, 64); }
      if (ok && (lane & 15) == 0){
        al_s[row*HEADSC + h] = ps;
        al_d[row*HEADSC + h] = pd;
      }
    }
  }
}

// bh transposed [bucket][block]: thread k reads 128 contiguous ints.
__global__ void __launch_bounds__(256) k_binscan(int* __restrict__ bh, int* __restrict__ bstart){
  __shared__ int buf[256];
  int tid = threadIdx.x;
  int tot = 0;
  if (tid < NBUCK)
    for (int b = 0; b < SBLK; b++) tot += bh[tid*SBLK + b];
  buf[tid] = (tid < NBUCK) ? tot : 0;
  __syncthreads();
  #pragma unroll
  for (int off = 1; off < 256; off <<= 1){
    int t = (tid >= off) ? buf[tid - off] : 0;
    __syncthreads();
    buf[tid] += t; __syncthreads();
  }
  int excl = buf[tid] - ((tid < NBUCK) ? tot : 0);
  if (tid < NBUCK) bstart[tid] = excl;
  if (tid == 0) bstart[NBUCK] = E_TOTC;
  __syncthreads();
  if (tid < NBUCK){
    int run = excl;
    for (int b = 0; b < SBLK; b++){
      int t = bh[tid*SBLK + b];
      bh[tid*SBLK + b] = run;
      run += t;
    }
  }
}

__global__ void __launch_bounds__(256) k_binB(const int* __restrict__ ei, const int* __restrict__ bh,
                                              unsigned int* __restrict__ binbuf){
  __shared__ int h[NBUCK];
  int tid = threadIdx.x, b = blockIdx.x;
  for (int i = tid; i < NBUCK; i += 256) h[i] = bh[i*SBLK + b];
  __syncthreads();
  int e0 = b*CHUNK, e1 = e0 + CHUNK; if (e1 > E_TOTC) e1 = E_TOTC;
  for (int e = e0 + tid; e < e1; e += 256){
    int s, d;
    if (e < E0C){ d = ei[E0C + e]; s = ei[e]; }
    else { s = e - E0C; d = s; }
    int pos = atomicAdd(&h[d >> 8], 1);
    binbuf[pos] = ((unsigned int)d << 16) | (unsigned int)s;
  }
}

__global__ void __launch_bounds__(256) k_binC(const unsigned int* __restrict__ binbuf,
                                              const int* __restrict__ bstart,
                                              int* __restrict__ rp, unsigned short* __restrict__ srcs){
  __shared__ int lcnt[BNODES];
  __shared__ int buf[BNODES];
  __shared__ int pfx[BNODES];
  int tid = threadIdx.x, k = blockIdx.x;
  int lo = k * BNODES;
  int b0 = bstart[k], b1 = bstart[k+1];
  lcnt[tid] = 0;
  __syncthreads();
  for (int i = b0 + tid; i < b1; i += 256){
    int d = binbuf[i] >> 16;
    atomicAdd(&lcnt[d - lo], 1);
  }
  __syncthreads();
  int v = lcnt[tid];
  buf[tid] = v;
  __syncthreads();
  #pragma unroll
  for (int off = 1; off < 256; off <<= 1){
    int t = (tid >= off) ? buf[tid - off] : 0;
    __syncthreads();
    buf[tid] += t; __syncthreads();
  }
  int excl = buf[tid] - v;
  pfx[tid] = excl;
  int node = lo + tid;
  if (node < N_NODESC) rp[node] = b0 + excl;
  if (k == 0 && tid == 0) rp[N_NODESC] = E_TOTC;
  lcnt[tid] = 0;
  __syncthreads();
  for (int i = b0 + tid; i < b1; i += 256){
    unsigned int u = binbuf[i];
    int d = u >> 16;
    int r = atomicAdd(&lcnt[d - lo], 1);
    srcs[b0 + pfx[d - lo] + r] = (unsigned short)(u & 0xffffu);
  }
}

// Layer-1, single pass; hout written as packed bf16 pairs.
__global__ void __launch_bounds__(256) k_node1(const unsigned int* __restrict__ h1b,
        const float* __restrict__ al_s, const float* __restrict__ al_d,
        const int* __restrict__ rp, const unsigned short* __restrict__ srcs,
        const float* __restrict__ b1, unsigned int* __restrict__ houtb)
{
  int wave = threadIdx.x >> 6, lane = threadIdx.x & 63;
  int n = blockIdx.x*4 + wave;
  if (n >= N_NODESC) return;
  int beg = rp[n], end = rp[n+1];
  int h = lane >> 4;
  float adh = al_d[n*4 + h];
  float dsum = 0.f, acc0 = 0.f, acc1 = 0.f;
  #pragma unroll 8
  for (int p = beg; p < end; p++){
    int s = srcs[p];
    float a = __expf(lrelu(al_s[s*4 + h] + adh));
    unsigned int u = h1b[(size_t)s*64 + lane];
    dsum += a;
    acc0 = fmaf(a, bf2f(u & 0xffffu), acc0);
    acc1 = fmaf(a, bf2f(u >> 16), acc1);
  }
  float inv = 1.f / (dsum + 1e-16f);
  int c0 = lane*2;
  float o0 = acc0*inv + b1[c0], o1 = acc1*inv + b1[c0+1];
  o0 = o0 > 0.f ? o0 : __expf(o0) - 1.f;   // ELU
  o1 = o1 > 0.f ? o1 : __expf(o1) - 1.f;
  houtb[(size_t)n*64 + lane] = f2bf(o0) | (f2bf(o1) << 16);
}

// h2 = hout @ W2 (hout packed bf16 in, h2 packed bf16 out); attention logits. 4 rows/wave.
__global__ void __launch_bounds__(256) k_gemm2(const unsigned int* __restrict__ hinb, const float* __restrict__ W2,
        const float* __restrict__ a_s, const float* __restrict__ a_d,
        unsigned int* __restrict__ h2b, float* __restrict__ al_s, float* __restrict__ al_d)
{
  __shared__ __align__(16) float Wl[IN_CHC*OUT_CHC];   // 8 KB
  __shared__ __align__(16) float xr[4][4][IN_CHC];     // 8 KB
  int tid = threadIdx.x;
  for (int i = tid*4; i < IN_CHC*OUT_CHC; i += 256*4)
    *(float4*)&Wl[i] = *(const float4*)&W2[i];
  __syncthreads();
  int wave = tid >> 6, lane = tid & 63;
  int r = lane >> 4, c = lane & 15;
  int row0 = blockIdx.x*16 + wave*4;
  for (int rr = 0; rr < 4; rr++){
    unsigned int u = hinb[(size_t)(row0+rr)*64 + lane];
    xr[wave][rr][lane*2]   = bf2f(u & 0xffffu);
    xr[wave][rr][lane*2+1] = bf2f(u >> 16);
  }
  float acc = 0.f;
  #pragma unroll 8
  for (int k = 0; k < IN_CHC; k++)
    acc = fmaf(xr[wave][r][k], Wl[k*OUT_CHC + c], acc);
  int row = row0 + r;
  float other = __shfl_xor(acc, 1, 64);     // partner channel (c^1)
  if ((c & 1) == 0)
    h2b[(size_t)row*8 + (c >> 1)] = f2bf(acc) | (f2bf(other) << 16);
  float ps = acc * a_s[c];
  float pd = acc * a_d[c];
  #pragma unroll
  for (int m = 1; m < 16; m <<= 1){ ps += __shfl_xor(ps, m, 64); pd += __shfl_xor(pd, m, 64); }
  if (c == 0){ al_s[row] = ps; al_d[row] = pd; }
}

// Layer-2, single pass: 4 groups stride every 4th edge; h2 gathered as bf16 pairs.
__global__ void __launch_bounds__(256) k_node2(const unsigned int* __restrict__ h2b,
        const float* __restrict__ al_s, const float* __restrict__ al_d,
        const int* __restrict__ rp, const unsigned short* __restrict__ srcs,
        const float* __restrict__ b2, float* __restrict__ out)
{
  int wave = threadIdx.x >> 6, lane = threadIdx.x & 63;
  int n = blockIdx.x*4 + wave;
  if (n >= N_NODESC) return;
  int beg = rp[n], end = rp[n+1];
  float ad = al_d[n];
  int c = lane & 15, jg = lane >> 4;
  unsigned int hi = (c & 1);
  int widx = c >> 1;
  float dsum = 0.f, acc = 0.f;
  #pragma unroll 4
  for (int p = beg + jg; p < end; p += 4){
    int s = srcs[p];
    float a = __expf(lrelu(al_s[s] + ad));
    unsigned int u = h2b[(size_t)s*8 + widx];
    float hv = __uint_as_float(hi ? (u & 0xFFFF0000u) : (u << 16));
    dsum += a;
    acc = fmaf(a, hv, acc);
  }
  dsum += __shfl_xor(dsum, 16, 64);
  dsum += __shfl_xor(dsum, 32, 64);
  acc += __shfl_xor(acc, 16, 64);
  acc += __shfl_xor(acc, 32, 64);
  float inv = 1.f / (dsum + 1e-16f);
  float v = acc*inv + b2[c];
  float mm = v;
  #pragma unroll
  for (int o = 1; o < 16; o <<= 1) mm = fmaxf(mm, __shfl_xor(mm, o, 64));
  float se = __expf(v - mm);
  #pragma unroll
  for (int o = 1; o < 16; o <<= 1) se += __shfl_xor(se, o, 64);
  if (jg == 0) out[n*OUT_CHC + c] = v - mm - __logf(se);
}

extern "C" void kernel_launch(void* const* d_in, const int* in_sizes, int n_in,
                              void* d_out, int out_size, void* d_ws, size_t ws_size,
                              hipStream_t stream)
{
  const float* x   = (const float*)d_in[0];
  const int*   ei  = (const int*)d_in[1];
  // d_in[2] edge_attr: ignored (PyG GATConv with edge_dim=None)
  const float* W1  = (const float*)d_in[3];
  const float* as1 = (const float*)d_in[4];
  const float* ad1 = (const float*)d_in[5];
  const float* b1  = (const float*)d_in[6];
  const float* W2  = (const float*)d_in[7];
  const float* as2 = (const float*)d_in[8];
  const float* ad2 = (const float*)d_in[9];
  const float* b2  = (const float*)d_in[10];
  float* out = (float*)d_out;

  char* ws = (char*)d_ws;
  size_t off = 0;
  auto alloc = [&](size_t bytes)->void*{
    void* p = ws + off;
    off = (off + bytes + 255) & ~(size_t)255;
    return p;
  };
  unsigned int* h1b = (unsigned int*)alloc((size_t)N_NODESC*64*4);   // bf16-packed, 12.8 MB
  unsigned int* houtb = (unsigned int*)alloc((size_t)N_NODESC*64*4); // bf16-packed, 12.8 MB
  float* al_s1 = (float*)alloc((size_t)N_NODESC*HEADSC*4);
  float* al_d1 = (float*)alloc((size_t)N_NODESC*HEADSC*4);
  unsigned int* h2b = (unsigned int*)alloc((size_t)N_NODESC*8*4);    // bf16-packed, 1.6 MB
  float* al_s2 = (float*)alloc((size_t)N_NODESC*4);
  float* al_d2 = (float*)alloc((size_t)N_NODESC*4);
  int* rp      = (int*)alloc((size_t)(N_NODESC+1)*4);
  unsigned short* srcs = (unsigned short*)alloc((size_t)E_TOTC*2);  // 1.7 MB
  int* bh      = (int*)alloc((size_t)SBLK*NBUCK*4);        // 100 KB
  int* bstart  = (int*)alloc((size_t)(NBUCK+1)*4);
  unsigned int* binbuf = (unsigned int*)alloc((size_t)E_TOTC*4);    // 3.4 MB
  unsigned short* Wp = (unsigned short*)alloc((size_t)IN_CHC*HCC*2); // 32 KB

  k_prep<<<1, 256, 0, stream>>>(W1, Wp);
  k_gemm1A<<<NG1 + SBLK, 256, 0, stream>>>(x, Wp, as1, ad1, h1b, al_s1, al_d1, ei, bh);
  k_binscan<<<1, 256, 0, stream>>>(bh, bstart);
  k_binB<<<SBLK, 256, 0, stream>>>(ei, bh, binbuf);
  k_binC<<<NBUCK, 256, 0, stream>>>(binbuf, bstart, rp, srcs);
  k_node1<<<N_NODESC/4, 256, 0, stream>>>(h1b, al_s1, al_d1, rp, srcs, b1, houtb);
  k_gemm2<<<N_NODESC/16, 256, 0, stream>>>(houtb, W2, as2, ad2, h2b, al_s2, al_d2);
  k_node2<<<N_NODESC/4, 256, 0, stream>>>(h2b, al_s2, al_d2, rp, srcs, b2, out);
}

// Round 19
// 140.027 us; speedup vs baseline: 1.0979x; 1.0979x over previous
//
#include <hip/hip_runtime.h>

#define N_NODESC 50000
#define E0C      800000
#define E_TOTC   850000
#define IN_CHC   128
#define HCC      128   // HEADS*HID
#define HEADSC   4
#define OUT_CHC  16
#define NEG_SLOPE 0.2f
#define G1M      64                          // rows per block in k_gemm1 (MFMA)
#define NG1      ((N_NODESC + G1M - 1)/G1M)  // 782 gemm blocks
#define NBUCK    196                         // ceil(50000/256) dst buckets
#define BNODES   256                         // nodes per bucket (dst>>8)
#define SBLK     128                         // binning blocks
#define CHUNK    6656                        // edges per binning block (128*6656 >= 850000)

typedef __attribute__((ext_vector_type(8))) short bf16x8;
typedef __attribute__((ext_vector_type(4))) float f32x4;

__device__ __forceinline__ float lrelu(float v){ return v > 0.f ? v : NEG_SLOPE * v; }

__device__ __forceinline__ unsigned int f2bf(float f){
  unsigned int b = __float_as_uint(f);
  return (b + 0x7fffu + ((b >> 16) & 1u)) >> 16;
}
__device__ __forceinline__ float bf2f(unsigned int lo16){
  return __uint_as_float(lo16 << 16);
}

// Fused: blocks [0,NG1) do MFMA x@W1; blocks [NG1,NG1+SBLK) do binA histogram.
__global__ void __launch_bounds__(256) k_gemm1A(const float* __restrict__ x, const float* __restrict__ W1,
        const float* __restrict__ a_s, const float* __restrict__ a_d,
        unsigned int* __restrict__ h1b, float* __restrict__ al_s, float* __restrict__ al_d,
        const int* __restrict__ ei, int* __restrict__ bh)
{
  __shared__ __align__(16) unsigned short Wt[IN_CHC*HCC];  // [n][k], swizzled
  __shared__ __align__(16) unsigned short xt[G1M*IN_CHC];  // [m][k], swizzled
  __shared__ int hh[NBUCK];
  int tid = threadIdx.x, lane = tid & 63, wave = tid >> 6;

  if (blockIdx.x >= NG1){            // ---- binA role ----
    int b = blockIdx.x - NG1;
    for (int i = tid; i < NBUCK; i += 256) hh[i] = 0;
    __syncthreads();
    int e0 = b*CHUNK, e1 = e0 + CHUNK; if (e1 > E_TOTC) e1 = E_TOTC;
    for (int e = e0 + tid; e < e1; e += 256){
      int d = (e < E0C) ? ei[E0C + e] : (e - E0C);
      atomicAdd(&hh[d >> 8], 1);
    }
    __syncthreads();
    for (int i = tid; i < NBUCK; i += 256) bh[b*NBUCK + i] = hh[i];
    return;
  }

  // ---- gemm role ----
  int row0 = blockIdx.x * G1M;
  for (int n0 = 0; n0 < 128; n0 += 64){
    int n = n0 + wave*16 + (lane & 15);
    for (int kc = 0; kc < 128; kc += 32){
      int k = kc + (lane >> 4)*8;
      unsigned int u[4];
      #pragma unroll
      for (int j = 0; j < 8; j += 2){
        float a = W1[(size_t)(k+j)*HCC + n];
        float b = W1[(size_t)(k+j+1)*HCC + n];
        u[j>>1] = f2bf(a) | (f2bf(b) << 16);
      }
      int idx = (n*128 + k) ^ ((n & 7) << 3);
      *(uint4*)&Wt[idx] = make_uint4(u[0],u[1],u[2],u[3]);
    }
  }
  {
    int r  = tid >> 2;
    int kc = (tid & 3) * 32;
    int rr = row0 + r; if (rr > N_NODESC-1) rr = N_NODESC-1;
    const float* xp = &x[(size_t)rr*IN_CHC + kc];
    #pragma unroll
    for (int j = 0; j < 32; j += 8){
      unsigned int u0 = f2bf(xp[j+0]) | (f2bf(xp[j+1]) << 16);
      unsigned int u1 = f2bf(xp[j+2]) | (f2bf(xp[j+3]) << 16);
      unsigned int u2 = f2bf(xp[j+4]) | (f2bf(xp[j+5]) << 16);
      unsigned int u3 = f2bf(xp[j+6]) | (f2bf(xp[j+7]) << 16);
      int idx = (r*128 + kc + j) ^ ((r & 7) << 3);
      *(uint4*)&xt[idx] = make_uint4(u0,u1,u2,u3);
    }
  }
  __syncthreads();

  int rw = wave * 16;
  f32x4 acc[8];
  #pragma unroll
  for (int t = 0; t < 8; t++) acc[t] = (f32x4){0.f,0.f,0.f,0.f};
  #pragma unroll
  for (int kk = 0; kk < 128; kk += 32){
    int m  = rw + (lane & 15);
    int ks = kk + (lane >> 4)*8;
    bf16x8 afrag = *(bf16x8*)&xt[(m*128 + ks) ^ ((m & 7) << 3)];
    #pragma unroll
    for (int t = 0; t < 8; t++){
      int n = t*16 + (lane & 15);
      bf16x8 bfrag = *(bf16x8*)&Wt[(n*128 + ks) ^ ((n & 7) << 3)];
      acc[t] = __builtin_amdgcn_mfma_f32_16x16x32_bf16(afrag, bfrag, acc[t], 0, 0, 0);
    }
  }

  float asv[8], adv[8];
  #pragma unroll
  for (int t = 0; t < 8; t++){
    asv[t] = a_s[t*16 + (lane & 15)];
    adv[t] = a_d[t*16 + (lane & 15)];
  }
  #pragma unroll
  for (int r = 0; r < 4; r++){
    int row = row0 + rw + (lane >> 4)*4 + r;
    bool ok = (row < N_NODESC);
    #pragma unroll
    for (int t = 0; t < 8; t++){
      float v = acc[t][r];
      float o = __shfl_xor(v, 1, 64);
      int c = t*16 + (lane & 15);
      if (ok && ((c & 1) == 0))
        h1b[(size_t)row*64 + (c >> 1)] = f2bf(v) | (f2bf(o) << 16);
    }
    #pragma unroll
    for (int h = 0; h < 4; h++){
      float ps = acc[2*h][r]*asv[2*h] + acc[2*h+1][r]*asv[2*h+1];
      float pd = acc[2*h][r]*adv[2*h] + acc[2*h+1][r]*adv[2*h+1];
      #pragma unroll
      for (int m = 1; m < 16; m <<= 1){ ps += __shfl_xor(ps, m, 64); pd += __shfl_xor(pd, m, 64); }
      if (ok && (lane & 15) == 0){
        al_s[row*HEADSC + h] = ps;
        al_d[row*HEADSC + h] = pd;
      }
    }
  }
}

__global__ void __launch_bounds__(256) k_binscan(int* __restrict__ bh, int* __restrict__ bstart){
  __shared__ int buf[256];
  int tid = threadIdx.x;
  int tot = 0;
  if (tid < NBUCK)
    for (int b = 0; b < SBLK; b++) tot += bh[b*NBUCK + tid];
  buf[tid] = (tid < NBUCK) ? tot : 0;
  __syncthreads();
  #pragma unroll
  for (int off = 1; off < 256; off <<= 1){
    int t = (tid >= off) ? buf[tid - off] : 0;
    __syncthreads();
    buf[tid] += t; __syncthreads();
  }
  int excl = buf[tid] - ((tid < NBUCK) ? tot : 0);
  if (tid < NBUCK) bstart[tid] = excl;
  if (tid == 0) bstart[NBUCK] = E_TOTC;
  __syncthreads();
  if (tid < NBUCK){
    int run = excl;
    for (int b = 0; b < SBLK; b++){
      int t = bh[b*NBUCK + tid];
      bh[b*NBUCK + tid] = run;
      run += t;
    }
  }
}

__global__ void __launch_bounds__(256) k_binB(const int* __restrict__ ei, const int* __restrict__ bh,
                                              unsigned int* __restrict__ binbuf){
  __shared__ int h[NBUCK];
  int tid = threadIdx.x, b = blockIdx.x;
  for (int i = tid; i < NBUCK; i += 256) h[i] = bh[b*NBUCK + i];
  __syncthreads();
  int e0 = b*CHUNK, e1 = e0 + CHUNK; if (e1 > E_TOTC) e1 = E_TOTC;
  for (int e = e0 + tid; e < e1; e += 256){
    int s, d;
    if (e < E0C){ d = ei[E0C + e]; s = ei[e]; }
    else { s = e - E0C; d = s; }
    int pos = atomicAdd(&h[d >> 8], 1);
    binbuf[pos] = ((unsigned int)d << 16) | (unsigned int)s;
  }
}

__global__ void __launch_bounds__(256) k_binC(const unsigned int* __restrict__ binbuf,
                                              const int* __restrict__ bstart,
                                              int* __restrict__ rp, unsigned short* __restrict__ srcs){
  __shared__ int lcnt[BNODES];
  __shared__ int buf[BNODES];
  __shared__ int pfx[BNODES];
  int tid = threadIdx.x, k = blockIdx.x;
  int lo = k * BNODES;
  int b0 = bstart[k], b1 = bstart[k+1];
  lcnt[tid] = 0;
  __syncthreads();
  for (int i = b0 + tid; i < b1; i += 256){
    int d = binbuf[i] >> 16;
    atomicAdd(&lcnt[d - lo], 1);
  }
  __syncthreads();
  int v = lcnt[tid];
  buf[tid] = v;
  __syncthreads();
  #pragma unroll
  for (int off = 1; off < 256; off <<= 1){
    int t = (tid >= off) ? buf[tid - off] : 0;
    __syncthreads();
    buf[tid] += t; __syncthreads();
  }
  int excl = buf[tid] - v;
  pfx[tid] = excl;
  int node = lo + tid;
  if (node < N_NODESC) rp[node] = b0 + excl;
  if (k == 0 && tid == 0) rp[N_NODESC] = E_TOTC;
  lcnt[tid] = 0;
  __syncthreads();
  for (int i = b0 + tid; i < b1; i += 256){
    unsigned int u = binbuf[i];
    int d = u >> 16;
    int r = atomicAdd(&lcnt[d - lo], 1);
    srcs[b0 + pfx[d - lo] + r] = (unsigned short)(u & 0xffffu);
  }
}

// Layer-1, single pass (round-13 structure); hout written as packed bf16 pairs.
__global__ void __launch_bounds__(256) k_node1(const unsigned int* __restrict__ h1b,
        const float* __restrict__ al_s, const float* __restrict__ al_d,
        const int* __restrict__ rp, const unsigned short* __restrict__ srcs,
        const float* __restrict__ b1, unsigned int* __restrict__ houtb)
{
  int wave = threadIdx.x >> 6, lane = threadIdx.x & 63;
  int n = blockIdx.x*4 + wave;
  if (n >= N_NODESC) return;
  int beg = rp[n], end = rp[n+1];
  int h = lane >> 4;
  float adh = al_d[n*4 + h];
  float dsum = 0.f, acc0 = 0.f, acc1 = 0.f;
  #pragma unroll 4
  for (int p = beg; p < end; p++){
    int s = srcs[p];
    float a = __expf(lrelu(al_s[s*4 + h] + adh));
    unsigned int u = h1b[(size_t)s*64 + lane];
    dsum += a;
    acc0 = fmaf(a, bf2f(u & 0xffffu), acc0);
    acc1 = fmaf(a, bf2f(u >> 16), acc1);
  }
  float inv = 1.f / (dsum + 1e-16f);
  int c0 = lane*2;
  float o0 = acc0*inv + b1[c0], o1 = acc1*inv + b1[c0+1];
  o0 = o0 > 0.f ? o0 : __expf(o0) - 1.f;   // ELU
  o1 = o1 > 0.f ? o1 : __expf(o1) - 1.f;
  houtb[(size_t)n*64 + lane] = f2bf(o0) | (f2bf(o1) << 16);
}

// h2 = hout @ W2 (hout packed bf16 in, h2 packed bf16 out); attention logits. 4 rows/wave.
__global__ void __launch_bounds__(256) k_gemm2(const unsigned int* __restrict__ hinb, const float* __restrict__ W2,
        const float* __restrict__ a_s, const float* __restrict__ a_d,
        unsigned int* __restrict__ h2b, float* __restrict__ al_s, float* __restrict__ al_d)
{
  __shared__ __align__(16) float Wl[IN_CHC*OUT_CHC];   // 8 KB
  __shared__ __align__(16) float xr[4][4][IN_CHC];     // 8 KB
  int tid = threadIdx.x;
  for (int i = tid*4; i < IN_CHC*OUT_CHC; i += 256*4)
    *(float4*)&Wl[i] = *(const float4*)&W2[i];
  __syncthreads();
  int wave = tid >> 6, lane = tid & 63;
  int r = lane >> 4, c = lane & 15;
  int row0 = blockIdx.x*16 + wave*4;
  for (int rr = 0; rr < 4; rr++){
    unsigned int u = hinb[(size_t)(row0+rr)*64 + lane];
    xr[wave][rr][lane*2]   = bf2f(u & 0xffffu);
    xr[wave][rr][lane*2+1] = bf2f(u >> 16);
  }
  float acc = 0.f;
  #pragma unroll 8
  for (int k = 0; k < IN_CHC; k++)
    acc = fmaf(xr[wave][r][k], Wl[k*OUT_CHC + c], acc);
  int row = row0 + r;
  float other = __shfl_xor(acc, 1, 64);     // partner channel (c^1)
  if ((c & 1) == 0)
    h2b[(size_t)row*8 + (c >> 1)] = f2bf(acc) | (f2bf(other) << 16);
  float ps = acc * a_s[c];
  float pd = acc * a_d[c];
  #pragma unroll
  for (int m = 1; m < 16; m <<= 1){ ps += __shfl_xor(ps, m, 64); pd += __shfl_xor(pd, m, 64); }
  if (c == 0){ al_s[row] = ps; al_d[row] = pd; }
}

// Layer-2, single pass: 4 groups stride every 4th edge; h2 gathered as bf16 pairs.
__global__ void __launch_bounds__(256) k_node2(const unsigned int* __restrict__ h2b,
        const float* __restrict__ al_s, const float* __restrict__ al_d,
        const int* __restrict__ rp, const unsigned short* __restrict__ srcs,
        const float* __restrict__ b2, float* __restrict__ out)
{
  int wave = threadIdx.x >> 6, lane = threadIdx.x & 63;
  int n = blockIdx.x*4 + wave;
  if (n >= N_NODESC) return;
  int beg = rp[n], end = rp[n+1];
  float ad = al_d[n];
  int c = lane & 15, jg = lane >> 4;
  unsigned int hi = (c & 1);
  int widx = c >> 1;
  float dsum = 0.f, acc = 0.f;
  #pragma unroll 4
  for (int p = beg + jg; p < end; p += 4){
    int s = srcs[p];
    float a = __expf(lrelu(al_s[s] + ad));
    unsigned int u = h2b[(size_t)s*8 + widx];
    float hv = __uint_as_float(hi ? (u & 0xFFFF0000u) : (u << 16));
    dsum += a;
    acc = fmaf(a, hv, acc);
  }
  dsum += __shfl_xor(dsum, 16, 64);
  dsum += __shfl_xor(dsum, 32, 64);
  acc += __shfl_xor(acc, 16, 64);
  acc += __shfl_xor(acc, 32, 64);
  float inv = 1.f / (dsum + 1e-16f);
  float v = acc*inv + b2[c];
  float mm = v;
  #pragma unroll
  for (int o = 1; o < 16; o <<= 1) mm = fmaxf(mm, __shfl_xor(mm, o, 64));
  float se = __expf(v - mm);
  #pragma unroll
  for (int o = 1; o < 16; o <<= 1) se += __shfl_xor(se, o, 64);
  if (jg == 0) out[n*OUT_CHC + c] = v - mm - __logf(se);
}

extern "C" void kernel_launch(void* const* d_in, const int* in_sizes, int n_in,
                              void* d_out, int out_size, void* d_ws, size_t ws_size,
                              hipStream_t stream)
{
  const float* x   = (const float*)d_in[0];
  const int*   ei  = (const int*)d_in[1];
  // d_in[2] edge_attr: ignored (PyG GATConv with edge_dim=None)
  const float* W1  = (const float*)d_in[3];
  const float* as1 = (const float*)d_in[4];
  const float* ad1 = (const float*)d_in[5];
  const float* b1  = (const float*)d_in[6];
  const float* W2  = (const float*)d_in[7];
  const float* as2 = (const float*)d_in[8];
  const float* ad2 = (const float*)d_in[9];
  const float* b2  = (const float*)d_in[10];
  float* out = (float*)d_out;

  char* ws = (char*)d_ws;
  size_t off = 0;
  auto alloc = [&](size_t bytes)->void*{
    void* p = ws + off;
    off = (off + bytes + 255) & ~(size_t)255;
    return p;
  };
  unsigned int* h1b = (unsigned int*)alloc((size_t)N_NODESC*64*4);   // bf16-packed, 12.8 MB
  unsigned int* houtb = (unsigned int*)alloc((size_t)N_NODESC*64*4); // bf16-packed, 12.8 MB
  float* al_s1 = (float*)alloc((size_t)N_NODESC*HEADSC*4);
  float* al_d1 = (float*)alloc((size_t)N_NODESC*HEADSC*4);
  unsigned int* h2b = (unsigned int*)alloc((size_t)N_NODESC*8*4);    // bf16-packed, 1.6 MB
  float* al_s2 = (float*)alloc((size_t)N_NODESC*4);
  float* al_d2 = (float*)alloc((size_t)N_NODESC*4);
  int* rp      = (int*)alloc((size_t)(N_NODESC+1)*4);
  unsigned short* srcs = (unsigned short*)alloc((size_t)E_TOTC*2);  // 1.7 MB
  int* bh      = (int*)alloc((size_t)SBLK*NBUCK*4);        // 100 KB
  int* bstart  = (int*)alloc((size_t)(NBUCK+1)*4);
  unsigned int* binbuf = (unsigned int*)alloc((size_t)E_TOTC*4);    // 3.4 MB

  k_gemm1A<<<NG1 + SBLK, 256, 0, stream>>>(x, W1, as1, ad1, h1b, al_s1, al_d1, ei, bh);
  k_binscan<<<1, 256, 0, stream>>>(bh, bstart);
  k_binB<<<SBLK, 256, 0, stream>>>(ei, bh, binbuf);
  k_binC<<<NBUCK, 256, 0, stream>>>(binbuf, bstart, rp, srcs);
  k_node1<<<N_NODESC/4, 256, 0, stream>>>(h1b, al_s1, al_d1, rp, srcs, b1, houtb);
  k_gemm2<<<N_NODESC/16, 256, 0, stream>>>(houtb, W2, as2, ad2, h2b, al_s2, al_d2);
  k_node2<<<N_NODESC/4, 256, 0, stream>>>(h2b, al_s2, al_d2, rp, srcs, b2, out);
}

// Round 20
// 137.413 us; speedup vs baseline: 1.1188x; 1.0190x over previous
//
#include <hip/hip_runtime.h>

#define N_NODESC 50000
#define E0C      800000
#define E_TOTC   850000
#define IN_CHC   128
#define HCC      128   // HEADS*HID
#define HEADSC   4
#define OUT_CHC  16
#define NEG_SLOPE 0.2f
#define G1M      64                          // rows per block (MFMA gemm)
#define NG1      ((N_NODESC + G1M - 1)/G1M)  // 782 gemm blocks
#define NBUCK    196                         // ceil(50000/256) dst buckets
#define BNODES   256                         // nodes per bucket (dst>>8)
#define SBLK     128                         // binning blocks
#define CHUNK    6656                        // edges per binning block

typedef __attribute__((ext_vector_type(8))) short bf16x8;
typedef __attribute__((ext_vector_type(4))) float f32x4;

__device__ __forceinline__ float lrelu(float v){ return v > 0.f ? v : NEG_SLOPE * v; }

__device__ __forceinline__ unsigned int f2bf(float f){
  unsigned int b = __float_as_uint(f);
  return (b + 0x7fffu + ((b >> 16) & 1u)) >> 16;
}
__device__ __forceinline__ float bf2f(unsigned int lo16){
  return __uint_as_float(lo16 << 16);
}

// Role-split kernel: blocks [0,ngemm) run a GEMM chunk (rows from gemmBase);
// blocks [ngemm,..) run CSR stage: 0=binA hist, 1=binscan, 2=binB, 3=binC.
// CSR LDS scratch aliases xt (needs <=3KB of the 16KB).
__global__ void __launch_bounds__(256) k_fused(const float* __restrict__ x, const float* __restrict__ W1,
        const float* __restrict__ a_s, const float* __restrict__ a_d,
        unsigned int* __restrict__ h1b, float* __restrict__ al_s, float* __restrict__ al_d,
        const int* __restrict__ ei, int* __restrict__ bh, int* __restrict__ bstart,
        unsigned int* __restrict__ binbuf, int* __restrict__ rp, unsigned short* __restrict__ srcs,
        int gemmBase, int ngemm, int stage)
{
  __shared__ __align__(16) unsigned short Wt[IN_CHC*HCC];  // [n][k], swizzled (32 KB)
  __shared__ __align__(16) unsigned short xt[G1M*IN_CHC];  // [m][k], swizzled (16 KB)
  int tid = threadIdx.x, lane = tid & 63, wave = tid >> 6;

  if ((int)blockIdx.x >= ngemm){     // ---- CSR role ----
    int cb = blockIdx.x - ngemm;
    int* sh = (int*)xt;              // scratch alias
    if (stage == 0){                 // binA: per-block bucket histogram
      for (int i = tid; i < NBUCK; i += 256) sh[i] = 0;
      __syncthreads();
      int e0 = cb*CHUNK, e1 = e0 + CHUNK; if (e1 > E_TOTC) e1 = E_TOTC;
      for (int e = e0 + tid; e < e1; e += 256){
        int d = (e < E0C) ? ei[E0C + e] : (e - E0C);
        atomicAdd(&sh[d >> 8], 1);
      }
      __syncthreads();
      for (int i = tid; i < NBUCK; i += 256) bh[cb*NBUCK + i] = sh[i];
    } else if (stage == 1){          // binscan: single block
      int tot = 0;
      if (tid < NBUCK)
        for (int b = 0; b < SBLK; b++) tot += bh[b*NBUCK + tid];
      sh[tid] = (tid < NBUCK) ? tot : 0;
      __syncthreads();
      #pragma unroll
      for (int off = 1; off < 256; off <<= 1){
        int t = (tid >= off) ? sh[tid - off] : 0;
        __syncthreads();
        sh[tid] += t; __syncthreads();
      }
      int excl = sh[tid] - ((tid < NBUCK) ? tot : 0);
      if (tid < NBUCK) bstart[tid] = excl;
      if (tid == 0) bstart[NBUCK] = E_TOTC;
      __syncthreads();
      if (tid < NBUCK){
        int run = excl;
        for (int b = 0; b < SBLK; b++){
          int t = bh[b*NBUCK + tid];
          bh[b*NBUCK + tid] = run;
          run += t;
        }
      }
    } else if (stage == 2){          // binB: bin write
      for (int i = tid; i < NBUCK; i += 256) sh[i] = bh[cb*NBUCK + i];
      __syncthreads();
      int e0 = cb*CHUNK, e1 = e0 + CHUNK; if (e1 > E_TOTC) e1 = E_TOTC;
      for (int e = e0 + tid; e < e1; e += 256){
        int s, d;
        if (e < E0C){ d = ei[E0C + e]; s = ei[e]; }
        else { s = e - E0C; d = s; }
        int pos = atomicAdd(&sh[d >> 8], 1);
        binbuf[pos] = ((unsigned int)d << 16) | (unsigned int)s;
      }
    } else {                         // binC: per-bucket rp + srcs
      int* lcnt = sh; int* buf = sh + 256; int* pfx = sh + 512;
      int k = cb;
      int lo = k * BNODES;
      int b0 = bstart[k], b1 = bstart[k+1];
      lcnt[tid] = 0;
      __syncthreads();
      for (int i = b0 + tid; i < b1; i += 256){
        int d = binbuf[i] >> 16;
        atomicAdd(&lcnt[d - lo], 1);
      }
      __syncthreads();
      int v = lcnt[tid];
      buf[tid] = v;
      __syncthreads();
      #pragma unroll
      for (int off = 1; off < 256; off <<= 1){
        int t = (tid >= off) ? buf[tid - off] : 0;
        __syncthreads();
        buf[tid] += t; __syncthreads();
      }
      int excl = buf[tid] - v;
      pfx[tid] = excl;
      int node = lo + tid;
      if (node < N_NODESC) rp[node] = b0 + excl;
      if (k == 0 && tid == 0) rp[N_NODESC] = E_TOTC;
      lcnt[tid] = 0;
      __syncthreads();
      for (int i = b0 + tid; i < b1; i += 256){
        unsigned int u = binbuf[i];
        int d = u >> 16;
        int r = atomicAdd(&lcnt[d - lo], 1);
        srcs[b0 + pfx[d - lo] + r] = (unsigned short)(u & 0xffffu);
      }
    }
    return;
  }

  // ---- gemm role ----
  int row0 = (gemmBase + blockIdx.x) * G1M;
  for (int n0 = 0; n0 < 128; n0 += 64){
    int n = n0 + wave*16 + (lane & 15);
    for (int kc = 0; kc < 128; kc += 32){
      int k = kc + (lane >> 4)*8;
      unsigned int u[4];
      #pragma unroll
      for (int j = 0; j < 8; j += 2){
        float a = W1[(size_t)(k+j)*HCC + n];
        float b = W1[(size_t)(k+j+1)*HCC + n];
        u[j>>1] = f2bf(a) | (f2bf(b) << 16);
      }
      int idx = (n*128 + k) ^ ((n & 7) << 3);
      *(uint4*)&Wt[idx] = make_uint4(u[0],u[1],u[2],u[3]);
    }
  }
  {
    int r  = tid >> 2;
    int kc = (tid & 3) * 32;
    int rr = row0 + r; if (rr > N_NODESC-1) rr = N_NODESC-1;
    const float* xp = &x[(size_t)rr*IN_CHC + kc];
    #pragma unroll
    for (int j = 0; j < 32; j += 8){
      unsigned int u0 = f2bf(xp[j+0]) | (f2bf(xp[j+1]) << 16);
      unsigned int u1 = f2bf(xp[j+2]) | (f2bf(xp[j+3]) << 16);
      unsigned int u2 = f2bf(xp[j+4]) | (f2bf(xp[j+5]) << 16);
      unsigned int u3 = f2bf(xp[j+6]) | (f2bf(xp[j+7]) << 16);
      int idx = (r*128 + kc + j) ^ ((r & 7) << 3);
      *(uint4*)&xt[idx] = make_uint4(u0,u1,u2,u3);
    }
  }
  __syncthreads();

  int rw = wave * 16;
  f32x4 acc[8];
  #pragma unroll
  for (int t = 0; t < 8; t++) acc[t] = (f32x4){0.f,0.f,0.f,0.f};
  #pragma unroll
  for (int kk = 0; kk < 128; kk += 32){
    int m  = rw + (lane & 15);
    int ks = kk + (lane >> 4)*8;
    bf16x8 afrag = *(bf16x8*)&xt[(m*128 + ks) ^ ((m & 7) << 3)];
    #pragma unroll
    for (int t = 0; t < 8; t++){
      int n = t*16 + (lane & 15);
      bf16x8 bfrag = *(bf16x8*)&Wt[(n*128 + ks) ^ ((n & 7) << 3)];
      acc[t] = __builtin_amdgcn_mfma_f32_16x16x32_bf16(afrag, bfrag, acc[t], 0, 0, 0);
    }
  }

  float asv[8], adv[8];
  #pragma unroll
  for (int t = 0; t < 8; t++){
    asv[t] = a_s[t*16 + (lane & 15)];
    adv[t] = a_d[t*16 + (lane & 15)];
  }
  #pragma unroll
  for (int r = 0; r < 4; r++){
    int row = row0 + rw + (lane >> 4)*4 + r;
    bool ok = (row < N_NODESC);
    #pragma unroll
    for (int t = 0; t < 8; t++){
      float v = acc[t][r];
      float o = __shfl_xor(v, 1, 64);
      int c = t*16 + (lane & 15);
      if (ok && ((c & 1) == 0))
        h1b[(size_t)row*64 + (c >> 1)] = f2bf(v) | (f2bf(o) << 16);
    }
    #pragma unroll
    for (int h = 0; h < 4; h++){
      float ps = acc[2*h][r]*asv[2*h] + acc[2*h+1][r]*asv[2*h+1];
      float pd = acc[2*h][r]*adv[2*h] + acc[2*h+1][r]*adv[2*h+1];
      #pragma unroll
      for (int m = 1; m < 16; m <<= 1){ ps += __shfl_xor(ps, m, 64); pd += __shfl_xor(pd, m, 64); }
      if (ok && (lane & 15) == 0){
        al_s[row*HEADSC + h] = ps;
        al_d[row*HEADSC + h] = pd;
      }
    }
  }
}

// Layer-1, single pass; hout written as packed bf16 pairs.
__global__ void __launch_bounds__(256) k_node1(const unsigned int* __restrict__ h1b,
        const float* __restrict__ al_s, const float* __restrict__ al_d,
        const int* __restrict__ rp, const unsigned short* __restrict__ srcs,
        const float* __restrict__ b1, unsigned int* __restrict__ houtb)
{
  int wave = threadIdx.x >> 6, lane = threadIdx.x & 63;
  int n = blockIdx.x*4 + wave;
  if (n >= N_NODESC) return;
  int beg = rp[n], end = rp[n+1];
  int h = lane >> 4;
  float adh = al_d[n*4 + h];
  float dsum = 0.f, acc0 = 0.f, acc1 = 0.f;
  #pragma unroll 4
  for (int p = beg; p < end; p++){
    int s = srcs[p];
    float a = __expf(lrelu(al_s[s*4 + h] + adh));
    unsigned int u = h1b[(size_t)s*64 + lane];
    dsum += a;
    acc0 = fmaf(a, bf2f(u & 0xffffu), acc0);
    acc1 = fmaf(a, bf2f(u >> 16), acc1);
  }
  float inv = 1.f / (dsum + 1e-16f);
  int c0 = lane*2;
  float o0 = acc0*inv + b1[c0], o1 = acc1*inv + b1[c0+1];
  o0 = o0 > 0.f ? o0 : __expf(o0) - 1.f;   // ELU
  o1 = o1 > 0.f ? o1 : __expf(o1) - 1.f;
  houtb[(size_t)n*64 + lane] = f2bf(o0) | (f2bf(o1) << 16);
}

// h2 = hout @ W2 (hout packed bf16 in, h2 packed bf16 out); attention logits. 4 rows/wave.
__global__ void __launch_bounds__(256) k_gemm2(const unsigned int* __restrict__ hinb, const float* __restrict__ W2,
        const float* __restrict__ a_s, const float* __restrict__ a_d,
        unsigned int* __restrict__ h2b, float* __restrict__ al_s, float* __restrict__ al_d)
{
  __shared__ __align__(16) float Wl[IN_CHC*OUT_CHC];   // 8 KB
  __shared__ __align__(16) float xr[4][4][IN_CHC];     // 8 KB
  int tid = threadIdx.x;
  for (int i = tid*4; i < IN_CHC*OUT_CHC; i += 256*4)
    *(float4*)&Wl[i] = *(const float4*)&W2[i];
  __syncthreads();
  int wave = tid >> 6, lane = tid & 63;
  int r = lane >> 4, c = lane & 15;
  int row0 = blockIdx.x*16 + wave*4;
  for (int rr = 0; rr < 4; rr++){
    unsigned int u = hinb[(size_t)(row0+rr)*64 + lane];
    xr[wave][rr][lane*2]   = bf2f(u & 0xffffu);
    xr[wave][rr][lane*2+1] = bf2f(u >> 16);
  }
  float acc = 0.f;
  #pragma unroll 8
  for (int k = 0; k < IN_CHC; k++)
    acc = fmaf(xr[wave][r][k], Wl[k*OUT_CHC + c], acc);
  int row = row0 + r;
  float other = __shfl_xor(acc, 1, 64);     // partner channel (c^1)
  if ((c & 1) == 0)
    h2b[(size_t)row*8 + (c >> 1)] = f2bf(acc) | (f2bf(other) << 16);
  float ps = acc * a_s[c];
  float pd = acc * a_d[c];
  #pragma unroll
  for (int m = 1; m < 16; m <<= 1){ ps += __shfl_xor(ps, m, 64); pd += __shfl_xor(pd, m, 64); }
  if (c == 0){ al_s[row] = ps; al_d[row] = pd; }
}

// Layer-2, single pass: 4 groups stride every 4th edge; h2 gathered as bf16 pairs.
__global__ void __launch_bounds__(256) k_node2(const unsigned int* __restrict__ h2b,
        const float* __restrict__ al_s, const float* __restrict__ al_d,
        const int* __restrict__ rp, const unsigned short* __restrict__ srcs,
        const float* __restrict__ b2, float* __restrict__ out)
{
  int wave = threadIdx.x >> 6, lane = threadIdx.x & 63;
  int n = blockIdx.x*4 + wave;
  if (n >= N_NODESC) return;
  int beg = rp[n], end = rp[n+1];
  float ad = al_d[n];
  int c = lane & 15, jg = lane >> 4;
  unsigned int hi = (c & 1);
  int widx = c >> 1;
  float dsum = 0.f, acc = 0.f;
  #pragma unroll 4
  for (int p = beg + jg; p < end; p += 4){
    int s = srcs[p];
    float a = __expf(lrelu(al_s[s] + ad));
    unsigned int u = h2b[(size_t)s*8 + widx];
    float hv = __uint_as_float(hi ? (u & 0xFFFF0000u) : (u << 16));
    dsum += a;
    acc = fmaf(a, hv, acc);
  }
  dsum += __shfl_xor(dsum, 16, 64);
  dsum += __shfl_xor(dsum, 32, 64);
  acc += __shfl_xor(acc, 16, 64);
  acc += __shfl_xor(acc, 32, 64);
  float inv = 1.f / (dsum + 1e-16f);
  float v = acc*inv + b2[c];
  float mm = v;
  #pragma unroll
  for (int o = 1; o < 16; o <<= 1) mm = fmaxf(mm, __shfl_xor(mm, o, 64));
  float se = __expf(v - mm);
  #pragma unroll
  for (int o = 1; o < 16; o <<= 1) se += __shfl_xor(se, o, 64);
  if (jg == 0) out[n*OUT_CHC + c] = v - mm - __logf(se);
}

extern "C" void kernel_launch(void* const* d_in, const int* in_sizes, int n_in,
                              void* d_out, int out_size, void* d_ws, size_t ws_size,
                              hipStream_t stream)
{
  const float* x   = (const float*)d_in[0];
  const int*   ei  = (const int*)d_in[1];
  // d_in[2] edge_attr: ignored (PyG GATConv with edge_dim=None)
  const float* W1  = (const float*)d_in[3];
  const float* as1 = (const float*)d_in[4];
  const float* ad1 = (const float*)d_in[5];
  const float* b1  = (const float*)d_in[6];
  const float* W2  = (const float*)d_in[7];
  const float* as2 = (const float*)d_in[8];
  const float* ad2 = (const float*)d_in[9];
  const float* b2  = (const float*)d_in[10];
  float* out = (float*)d_out;

  char* ws = (char*)d_ws;
  size_t off = 0;
  auto alloc = [&](size_t bytes)->void*{
    void* p = ws + off;
    off = (off + bytes + 255) & ~(size_t)255;
    return p;
  };
  unsigned int* h1b = (unsigned int*)alloc((size_t)N_NODESC*64*4);   // bf16-packed, 12.8 MB
  unsigned int* houtb = (unsigned int*)alloc((size_t)N_NODESC*64*4); // bf16-packed, 12.8 MB
  float* al_s1 = (float*)alloc((size_t)N_NODESC*HEADSC*4);
  float* al_d1 = (float*)alloc((size_t)N_NODESC*HEADSC*4);
  unsigned int* h2b = (unsigned int*)alloc((size_t)N_NODESC*8*4);    // bf16-packed, 1.6 MB
  float* al_s2 = (float*)alloc((size_t)N_NODESC*4);
  float* al_d2 = (float*)alloc((size_t)N_NODESC*4);
  int* rp      = (int*)alloc((size_t)(N_NODESC+1)*4);
  unsigned short* srcs = (unsigned short*)alloc((size_t)E_TOTC*2);  // 1.7 MB
  int* bh      = (int*)alloc((size_t)SBLK*NBUCK*4);        // 100 KB
  int* bstart  = (int*)alloc((size_t)(NBUCK+1)*4);
  unsigned int* binbuf = (unsigned int*)alloc((size_t)E_TOTC*4);    // 3.4 MB

  // 4 role-split launches: GEMM chunks (196+196+196+194=782) hide the CSR stages.
  k_fused<<<196 + SBLK, 256, 0, stream>>>(x, W1, as1, ad1, h1b, al_s1, al_d1,
        ei, bh, bstart, binbuf, rp, srcs, 0, 196, 0);
  k_fused<<<196 + 1, 256, 0, stream>>>(x, W1, as1, ad1, h1b, al_s1, al_d1,
        ei, bh, bstart, binbuf, rp, srcs, 196, 196, 1);
  k_fused<<<196 + SBLK, 256, 0, stream>>>(x, W1, as1, ad1, h1b, al_s1, al_d1,
        ei, bh, bstart, binbuf, rp, srcs, 392, 196, 2);
  k_fused<<<194 + NBUCK, 256, 0, stream>>>(x, W1, as1, ad1, h1b, al_s1, al_d1,
        ei, bh, bstart, binbuf, rp, srcs, 588, 194, 3);
  k_node1<<<N_NODESC/4, 256, 0, stream>>>(h1b, al_s1, al_d1, rp, srcs, b1, houtb);
  k_gemm2<<<N_NODESC/16, 256, 0, stream>>>(houtb, W2, as2, ad2, h2b, al_s2, al_d2);
  k_node2<<<N_NODESC/4, 256, 0, stream>>>(h2b, al_s2, al_d2, rp, srcs, b2, out);
}